// Round 15
// baseline (390.653 us; speedup 1.0000x reference)
//
#include <hip/hip_runtime.h>
#include <hip/hip_bf16.h>
#include <cstdint>
#include <cstddef>

#define BN_EPS 1e-3f

typedef __attribute__((ext_vector_type(8))) short bf16x8;
typedef __attribute__((ext_vector_type(4))) float f32x4;
typedef __attribute__((ext_vector_type(2))) float f32x2;
typedef __attribute__((ext_vector_type(2))) unsigned int u32x2;
typedef __attribute__((ext_vector_type(4))) unsigned int u32x4;
typedef __attribute__((ext_vector_type(4))) float f32x4e;

__device__ __forceinline__ float blo(unsigned u) {
  union { unsigned i; float f; } v; v.i = u << 16; return v.f;
}
__device__ __forceinline__ float bhi(unsigned u) {
  union { unsigned i; float f; } v; v.i = u & 0xffff0000u; return v.f;
}
__device__ __forceinline__ unsigned pk2(float a, float b) {
  __hip_bfloat162 t = __float22bfloat162_rn(make_float2(a, b));
  return *reinterpret_cast<unsigned*>(&t);
}
// fp8 e4m3 (gfx950 OCP) helpers — self-consistent HW round-trip
__device__ __forceinline__ unsigned char to_fp8(float f) {
  unsigned v = __builtin_amdgcn_cvt_pk_fp8_f32(f, f, 0, false);
  return (unsigned char)(v & 0xffu);
}
__device__ __forceinline__ void acc_fp8(float* acc, u32x2 u) {
  f32x2 p0 = __builtin_amdgcn_cvt_pk_f32_fp8(u.x, false);
  f32x2 p1 = __builtin_amdgcn_cvt_pk_f32_fp8(u.x, true);
  f32x2 p2 = __builtin_amdgcn_cvt_pk_f32_fp8(u.y, false);
  f32x2 p3 = __builtin_amdgcn_cvt_pk_f32_fp8(u.y, true);
  acc[0] += p0.x; acc[1] += p0.y; acc[2] += p1.x; acc[3] += p1.y;
  acc[4] += p2.x; acc[5] += p2.y; acc[6] += p3.x; acc[7] += p3.y;
}

// ---------------------------------------------------------------------------
// Embedding MFMA tile body (shared by fill_emb). Reads x fp32, cvt in-reg.
// hb = bf16(relu(x @ Wet^T + bias)); h8 = fp8(same). 64x128 tile, 4 waves.
// ---------------------------------------------------------------------------
__device__ __forceinline__ void emb_tile(
    const float* __restrict__ x,
    const __hip_bfloat16* __restrict__ Bt,   // [128][96]
    const float* __restrict__ bias,
    __hip_bfloat16* __restrict__ hb,
    unsigned char* __restrict__ h8, int N, int Fn, int m0, int tid)
{
  constexpr int KP = 96;
  const int w    = tid >> 6, lane = tid & 63;
  const int wr   = w >> 1,   wc   = w & 1;
  const int lr   = lane & 15;
  const int kg   = lane >> 4;

  f32x4 acc[2][4] = {};
  const int rowA0 = m0 + wr * 32 + lr;

  #pragma unroll
  for (int ks = 0; ks < KP / 32; ks++) {
    const int k0 = ks * 32 + kg * 8;
    bf16x8 a[2], b[4];
    #pragma unroll
    for (int m = 0; m < 2; m++) {
      int r = rowA0 + m * 16;
      r = (r < N) ? r : 0;
      const float* px = &x[(size_t)r * Fn + k0];
      float4 v0 = make_float4(0.f, 0.f, 0.f, 0.f);
      float4 v1 = make_float4(0.f, 0.f, 0.f, 0.f);
      if (k0 + 8 <= Fn) {
        v0 = *reinterpret_cast<const float4*>(px);
        v1 = *reinterpret_cast<const float4*>(px + 4);
      } else if (k0 + 4 <= Fn) {
        v0 = *reinterpret_cast<const float4*>(px);
        if (k0 + 5 <= Fn) v1.x = px[4];
        if (k0 + 6 <= Fn) v1.y = px[5];
        if (k0 + 7 <= Fn) v1.z = px[6];
      } else if (k0 < Fn) {
        if (k0 + 1 <= Fn) v0.x = px[0];
        if (k0 + 2 <= Fn) v0.y = px[1];
        if (k0 + 3 <= Fn) v0.z = px[2];
      }
      uint4 pu;
      pu.x = pk2(v0.x, v0.y); pu.y = pk2(v0.z, v0.w);
      pu.z = pk2(v1.x, v1.y); pu.w = pk2(v1.z, v1.w);
      a[m] = *reinterpret_cast<bf16x8*>(&pu);
    }
    #pragma unroll
    for (int n = 0; n < 4; n++) {
      int c = wc * 64 + n * 16 + lr;
      b[n] = *reinterpret_cast<const bf16x8*>(&Bt[(size_t)c * KP + k0]);
    }
    #pragma unroll
    for (int m = 0; m < 2; m++)
      #pragma unroll
      for (int n = 0; n < 4; n++)
        acc[m][n] = __builtin_amdgcn_mfma_f32_16x16x32_bf16(a[m], b[n], acc[m][n], 0, 0, 0);
  }

  #pragma unroll
  for (int n = 0; n < 4; n++) {
    const int c = wc * 64 + n * 16 + lr;
    const float bb = bias[c];
    #pragma unroll
    for (int m = 0; m < 2; m++) {
      #pragma unroll
      for (int j = 0; j < 4; j++) {
        int grow = m0 + wr * 32 + m * 16 + kg * 4 + j;
        if (grow < N) {
          float v = fmaxf(acc[m][n][j] + bb, 0.f);
          hb[(size_t)grow * 128 + c] = __float2bfloat16(v);
          h8[(size_t)grow * 128 + c] = to_fp8(v);
        }
      }
    }
  }
}

// ---------------------------------------------------------------------------
// Fused conv layer, bf16 residual chain, 32-row tiles, 16-deep gather MLP.
// fp8 shadow gather (128B/row). ALL streaming accesses (csr, eattr, Tb,
// residual, outputs) use non-temporal hints so the 4MB/XCD L2 retains h8
// (6.4MB unique, ~16 touches/row/layer) instead of thrashing on streams.
//   hbo = bf16( hbi + relu( (gather(h8i) ++ T) @ Wct / deg * bn_scale + ofs ) )
// GATHER_T=true (layer 0): T gathered from eattr (overlaps hb burst).
// ---------------------------------------------------------------------------
template<bool GATHER_T>
__global__ __launch_bounds__(256) void conv_fused(
    const __hip_bfloat16* __restrict__ hbi,
    const unsigned char* __restrict__ h8i,
    const int* __restrict__ row_ptr,
    const int* __restrict__ csr_col,
    const int* __restrict__ csr_eid,
    const float* __restrict__ eattr,
    __hip_bfloat16* __restrict__ Tb,          // [N][64] out (l0) / in (l1,l2)
    const __hip_bfloat16* __restrict__ Wct,   // [128][192]
    const float* __restrict__ bc,
    const float* __restrict__ gamma,
    const float* __restrict__ beta,
    __hip_bfloat16* __restrict__ hbo,
    unsigned char* __restrict__ h8o, int N)
{
  constexpr int K   = 192;
  constexpr int LDK = 200;
  __shared__ __hip_bfloat16 As[32 * LDK];   // 12.8 KB
  __shared__ float sinv[32];

  const int tid = threadIdx.x;
  const int m0  = blockIdx.x * 32;

  // ---- gather phase: 16 groups x 16 lanes, static 2 rows per group
  {
    const int g   = tid >> 4;
    const int gl  = tid & 15;
    const int gb  = (tid & 63) & ~15;    // group base lane within wave (for shfl)

    #pragma unroll
    for (int rr = 0; rr < 2; rr++) {
      const int r  = g + rr * 16;
      const int gr = m0 + r;
      float acc[8] = {};
      float tacc[4] = {};
      int len = 0;
      if (gr < N) {
        const int s = row_ptr[gr];
        len = row_ptr[gr + 1] - s;
        for (int b = 0; b < len; b += 16) {
          const int m  = min(16, len - b);
          const int cv = (gl < m) ? __builtin_nontemporal_load(&csr_col[s + b + gl]) : 0;
          int ev = 0;
          if (GATHER_T) ev = (gl < m) ? __builtin_nontemporal_load(&csr_eid[s + b + gl]) : 0;
          int j = 0;
          for (; j + 16 <= m; j += 16) {
            u32x2 u[16];
            #pragma unroll
            for (int t = 0; t < 16; t++) {
              int c = __shfl(cv, gb + j + t);
              u[t] = *reinterpret_cast<const u32x2*>(&h8i[(size_t)c * 128 + gl * 8]);
            }
            #pragma unroll
            for (int t = 0; t < 16; t++) acc_fp8(acc, u[t]);
          }
          for (; j + 8 <= m; j += 8) {
            u32x2 u[8];
            #pragma unroll
            for (int t = 0; t < 8; t++) {
              int c = __shfl(cv, gb + j + t);
              u[t] = *reinterpret_cast<const u32x2*>(&h8i[(size_t)c * 128 + gl * 8]);
            }
            #pragma unroll
            for (int t = 0; t < 8; t++) acc_fp8(acc, u[t]);
          }
          for (; j + 4 <= m; j += 4) {
            u32x2 u[4];
            #pragma unroll
            for (int t = 0; t < 4; t++) {
              int c = __shfl(cv, gb + j + t);
              u[t] = *reinterpret_cast<const u32x2*>(&h8i[(size_t)c * 128 + gl * 8]);
            }
            #pragma unroll
            for (int t = 0; t < 4; t++) acc_fp8(acc, u[t]);
          }
          for (; j < m; ++j) {
            int c = __shfl(cv, gb + j);
            u32x2 u = *reinterpret_cast<const u32x2*>(&h8i[(size_t)c * 128 + gl * 8]);
            acc_fp8(acc, u);
          }
          if (GATHER_T) {
            int j2 = 0;
            for (; j2 + 16 <= m; j2 += 16) {
              f32x4e t4[16];
              #pragma unroll
              for (int t = 0; t < 16; t++) {
                int e0 = __shfl(ev, gb + j2 + t);
                t4[t] = __builtin_nontemporal_load(
                    reinterpret_cast<const f32x4e*>(&eattr[(size_t)e0 * 64 + gl * 4]));
              }
              #pragma unroll
              for (int t = 0; t < 16; t++) {
                tacc[0] += t4[t].x; tacc[1] += t4[t].y;
                tacc[2] += t4[t].z; tacc[3] += t4[t].w;
              }
            }
            for (; j2 + 4 <= m; j2 += 4) {
              f32x4e t4[4];
              #pragma unroll
              for (int t = 0; t < 4; t++) {
                int e0 = __shfl(ev, gb + j2 + t);
                t4[t] = __builtin_nontemporal_load(
                    reinterpret_cast<const f32x4e*>(&eattr[(size_t)e0 * 64 + gl * 4]));
              }
              #pragma unroll
              for (int t = 0; t < 4; t++) {
                tacc[0] += t4[t].x; tacc[1] += t4[t].y;
                tacc[2] += t4[t].z; tacc[3] += t4[t].w;
              }
            }
            for (; j2 < m; ++j2) {
              int e0 = __shfl(ev, gb + j2);
              f32x4e t0 = __builtin_nontemporal_load(
                  reinterpret_cast<const f32x4e*>(&eattr[(size_t)e0 * 64 + gl * 4]));
              tacc[0] += t0.x; tacc[1] += t0.y; tacc[2] += t0.z; tacc[3] += t0.w;
            }
          }
        }
      }
      uint4 o;
      o.x = pk2(acc[0], acc[1]); o.y = pk2(acc[2], acc[3]);
      o.z = pk2(acc[4], acc[5]); o.w = pk2(acc[6], acc[7]);
      *reinterpret_cast<uint4*>(&As[r * LDK + gl * 8]) = o;
      if (GATHER_T) {
        u32x2 tw;
        tw.x = pk2(tacc[0], tacc[1]); tw.y = pk2(tacc[2], tacc[3]);
        *reinterpret_cast<u32x2*>(&As[r * LDK + 128 + gl * 4]) = tw;
        if (gr < N)
          __builtin_nontemporal_store(tw,
              reinterpret_cast<u32x2*>(&Tb[(size_t)gr * 64 + gl * 4]));
      }
      if (gl == 0) sinv[r] = 1.f / fmaxf(1.f, (float)len);
    }
  }
  if (!GATHER_T) {
    // ---- T-tile copy: 32 rows x 64 cols bf16 = 256 x 16B chunks
    int r   = tid >> 3;
    int ko  = (tid & 7) * 8;
    int gr  = m0 + r;
    u32x4 v = {0, 0, 0, 0};
    if (gr < N)
      v = __builtin_nontemporal_load(
          reinterpret_cast<const u32x4*>(&Tb[(size_t)gr * 64 + ko]));
    *reinterpret_cast<u32x4*>(&As[r * LDK + 128 + ko]) = v;
  }
  __syncthreads();

  // ---- MFMA phase: 4 waves, wave w owns cols [w*32, w*32+32)
  const int w    = tid >> 6, lane = tid & 63;
  const int lr   = lane & 15;
  const int kg   = lane >> 4;

  f32x4 acc[2][2] = {};
  #pragma unroll
  for (int ks = 0; ks < K / 32; ks++) {
    const int k0 = ks * 32 + kg * 8;
    bf16x8 a[2], b[2];
    #pragma unroll
    for (int m = 0; m < 2; m++)
      a[m] = *reinterpret_cast<const bf16x8*>(&As[(lr + m * 16) * LDK + k0]);
    #pragma unroll
    for (int n = 0; n < 2; n++) {
      int c = w * 32 + n * 16 + lr;
      b[n] = *reinterpret_cast<const bf16x8*>(&Wct[(size_t)c * K + k0]);
    }
    #pragma unroll
    for (int m = 0; m < 2; m++)
      #pragma unroll
      for (int n = 0; n < 2; n++)
        acc[m][n] = __builtin_amdgcn_mfma_f32_16x16x32_bf16(a[m], b[n], acc[m][n], 0, 0, 0);
  }

  const float rs = rsqrtf(1.f + BN_EPS);
  #pragma unroll
  for (int n = 0; n < 2; n++) {
    const int c   = w * 32 + n * 16 + lr;
    const float sc  = gamma[c] * rs;
    const float ofs = bc[c] * sc + beta[c];
    #pragma unroll
    for (int m = 0; m < 2; m++) {
      #pragma unroll
      for (int j = 0; j < 4; j++) {
        int lrow = m * 16 + kg * 4 + j;
        int grow = m0 + lrow;
        if (grow < N) {
          float v    = acc[m][n][j] * sc * sinv[lrow] + ofs;
          unsigned short hu = __builtin_nontemporal_load(
              reinterpret_cast<const unsigned short*>(&hbi[(size_t)grow * 128 + c]));
          float hold = blo((unsigned)hu);
          float hn   = hold + fmaxf(v, 0.f);
          __hip_bfloat16 hb16 = __float2bfloat16(hn);
          __builtin_nontemporal_store(*reinterpret_cast<unsigned short*>(&hb16),
              reinterpret_cast<unsigned short*>(&hbo[(size_t)grow * 128 + c]));
          __builtin_nontemporal_store(to_fp8(hn), &h8o[(size_t)grow * 128 + c]);
        }
      }
    }
  }
}

// ---------------------------------------------------------------------------
// K1: blocks [0,wb) convert weights; blocks [wb,..) histogram row degrees
// (cnt pre-zeroed by memsetAsync).
// ---------------------------------------------------------------------------
__global__ void prep_hist(
    const float* __restrict__ W_emb, __hip_bfloat16* __restrict__ Wet,
    const float* __restrict__ Wc, __hip_bfloat16* __restrict__ Wct,
    const int* __restrict__ rows, int* __restrict__ cnt,
    int E, int wb, int Fn, int Kp, int H, int L, int Kc)
{
  if ((int)blockIdx.x < wb) {
    int i = blockIdx.x * 256 + threadIdx.x;
    if (i < H * Kp) {
      int c = i / Kp, k = i - c * Kp;
      Wet[i] = __float2bfloat16(k < Fn ? W_emb[(size_t)k * H + c] : 0.f);
    } else if (i < H * Kp + L * H * Kc) {
      int j = i - H * Kp;
      int l   = j / (H * Kc);
      int rem = j - l * (H * Kc);
      int c   = rem / Kc;
      int k   = rem - c * Kc;
      Wct[j] = __float2bfloat16(Wc[(size_t)l * Kc * H + (size_t)k * H + c]);
    }
  } else {
    int e = (blockIdx.x - wb) * 256 + threadIdx.x;
    if (e < E) atomicAdd(&cnt[rows[e]], 1);
  }
}

// ---------------------------------------------------------------------------
// Multi-block scan, phase 1: per-block (2048 elems) local inclusive scan into
// row_ptr[idx+1]; block total into part[b].
// ---------------------------------------------------------------------------
__global__ __launch_bounds__(256) void scan_part(
    const int* __restrict__ cnt, int* __restrict__ row_ptr,
    int* __restrict__ part, int M)
{
  __shared__ int wsum[4];
  const int tid  = threadIdx.x;
  const int lane = tid & 63, wid = tid >> 6;
  const int base = blockIdx.x * 2048;

  int v[8]; int s = 0;
  #pragma unroll
  for (int i = 0; i < 8; i++) {
    int idx = base + tid * 8 + i;
    v[i] = (idx < M) ? cnt[idx] : 0;
    s += v[i];
  }
  int sc = s;
  #pragma unroll
  for (int o = 1; o < 64; o <<= 1) {
    int u = __shfl_up(sc, o);
    if (lane >= o) sc += u;
  }
  if (lane == 63) wsum[wid] = sc;
  __syncthreads();
  int woff = 0;
  #pragma unroll
  for (int i = 0; i < 4; i++) if (i < wid) woff += wsum[i];
  int run = woff + (sc - s);
  #pragma unroll
  for (int i = 0; i < 8; i++) {
    int idx = base + tid * 8 + i;
    run += v[i];
    if (idx < M) row_ptr[idx + 1] = run;
  }
  if (tid == 0) part[blockIdx.x] = wsum[0] + wsum[1] + wsum[2] + wsum[3];
}

// ---------------------------------------------------------------------------
// Multi-block scan, phase 2: add exclusive-prefix of part[] to each segment.
// ---------------------------------------------------------------------------
__global__ __launch_bounds__(256) void scan_add(
    int* __restrict__ row_ptr, const int* __restrict__ part, int M, int SB)
{
  __shared__ int soff;
  const int b   = blockIdx.x;
  const int tid = threadIdx.x;
  if (tid < 64) {
    int x = (tid < b) ? part[tid] : 0;   // SB <= 64 assumed
    #pragma unroll
    for (int o = 32; o > 0; o >>= 1) x += __shfl_down(x, o);
    if (tid == 0) { soff = x; if (b == 0) row_ptr[0] = 0; }
  }
  __syncthreads();
  const int off  = soff;
  const int base = b * 2048;
  if (off != 0) {
    #pragma unroll
    for (int i = 0; i < 8; i++) {
      int idx = base + i * 256 + tid;
      if (idx < M) row_ptr[idx + 1] += off;
    }
  }
}

// ---------------------------------------------------------------------------
// K3: blocks [0,fb) CSR-fill; blocks [fb,..) embedding MFMA tiles.
// ---------------------------------------------------------------------------
__global__ __launch_bounds__(256) void fill_emb(
    const int* __restrict__ rows, const int* __restrict__ cols,
    const int* __restrict__ row_ptr, int* __restrict__ fill_cnt,
    int* __restrict__ csr_col, int* __restrict__ csr_eid, int E, int fb,
    const float* __restrict__ x, const __hip_bfloat16* __restrict__ Wet,
    const float* __restrict__ b_emb, __hip_bfloat16* __restrict__ hb,
    unsigned char* __restrict__ h8, int N, int Fn)
{
  if ((int)blockIdx.x < fb) {
    int e = blockIdx.x * 256 + threadIdx.x;
    if (e < E) {
      int r   = rows[e];
      int pos = atomicAdd(&fill_cnt[r], 1);
      int at  = row_ptr[r] + pos;
      csr_col[at] = cols[e];
      csr_eid[at] = e;
    }
  } else {
    emb_tile(x, Wet, b_emb, hb, h8, N, Fn, (blockIdx.x - fb) * 64, threadIdx.x);
  }
}

// ---------------------------------------------------------------------------
// Per-graph mean pool (bf16 h) + hidden relu + output head. One 256-thread
// block per graph: 4-way row striping for the pool, split-K hidden layer.
// ---------------------------------------------------------------------------
__global__ __launch_bounds__(256) void pool_head(
    const __hip_bfloat16* __restrict__ hb, const int* __restrict__ batch,
    const float* __restrict__ Wh, const float* __restrict__ bh,
    const float* __restrict__ Wout, const float* __restrict__ bout,
    float* __restrict__ out, int N)
{
  const int g = blockIdx.x;
  const int t = threadIdx.x;
  int lo = 0, hi = N;
  while (lo < hi) { int mid = (lo + hi) >> 1; if (batch[mid] < g) lo = mid + 1; else hi = mid; }
  int start = lo;
  hi = N;
  while (lo < hi) { int mid = (lo + hi) >> 1; if (batch[mid] < g + 1) lo = mid + 1; else hi = mid; }
  int end = lo;

  const int lane = t & 63, q = t >> 6;   // 4 quarters
  float2 a0 = {0.f, 0.f}, a1 = {0.f, 0.f};
  int i = start + q;
  for (; i + 4 < end; i += 8) {
    unsigned u0 = *reinterpret_cast<const unsigned*>(&hb[(size_t)(i + 0) * 128 + lane * 2]);
    unsigned u1 = *reinterpret_cast<const unsigned*>(&hb[(size_t)(i + 4) * 128 + lane * 2]);
    a0.x += blo(u0); a0.y += bhi(u0);
    a1.x += blo(u1); a1.y += bhi(u1);
  }
  for (; i < end; i += 4) {
    unsigned u = *reinterpret_cast<const unsigned*>(&hb[(size_t)i * 128 + lane * 2]);
    a0.x += blo(u); a0.y += bhi(u);
  }
  float2 sum;
  sum.x = a0.x + a1.x;
  sum.y = a0.y + a1.y;

  __shared__ float2 part[4][64];
  __shared__ float  gl[128];
  part[q][lane] = sum;
  __syncthreads();
  if (t < 64) {
    float inv = 1.f / fmaxf(1.f, (float)(end - start));
    float2 tot;
    tot.x = ((part[0][t].x + part[1][t].x) + (part[2][t].x + part[3][t].x));
    tot.y = ((part[0][t].y + part[1][t].y) + (part[2][t].y + part[3][t].y));
    gl[2 * t]     = tot.x * inv;
    gl[2 * t + 1] = tot.y * inv;
  }
  __syncthreads();

  // hidden layer split-K: thread t handles output f = t&127, k-half = t>>7
  const int f    = t & 127;
  const int half = t >> 7;
  float acc = 0.f;
  #pragma unroll 4
  for (int k = half * 64; k < half * 64 + 64; k++) acc += gl[k] * Wh[k * 128 + f];
  __shared__ float ph[2][128];
  ph[half][f] = acc;
  __syncthreads();

  __shared__ float p[128];
  if (t < 128) {
    float v = fmaxf(ph[0][t] + ph[1][t] + bh[t], 0.f);
    p[t] = v * Wout[t];
  }
  __syncthreads();
  if (t < 64) {
    float v = p[t] + p[t + 64];
    #pragma unroll
    for (int o = 32; o > 0; o >>= 1) v += __shfl_down(v, o);
    if (t == 0) out[g] = v + bout[0];
  }
}

// ---------------------------------------------------------------------------
extern "C" void kernel_launch(void* const* d_in, const int* in_sizes, int n_in,
                              void* d_out, int out_size, void* d_ws, size_t ws_size,
                              hipStream_t stream)
{
  const float* x      = (const float*)d_in[0];
  const int*   eidx   = (const int*)d_in[1];
  const float* eattr  = (const float*)d_in[2];
  const int*   batch  = (const int*)d_in[3];
  const float* W_emb  = (const float*)d_in[4];
  const float* b_emb  = (const float*)d_in[5];
  const float* Wc     = (const float*)d_in[6];
  const float* bc     = (const float*)d_in[7];
  const float* gamma  = (const float*)d_in[8];
  const float* beta   = (const float*)d_in[9];
  const float* Wh     = (const float*)d_in[10];
  const float* bh     = (const float*)d_in[11];
  const float* Wout   = (const float*)d_in[12];
  const float* bout   = (const float*)d_in[13];
  float* out = (float*)d_out;

  const int N  = in_sizes[3];
  const int E  = in_sizes[1] / 2;
  const int Fn = in_sizes[0] / N;      // 92
  const int H  = in_sizes[5];          // 128
  const int L  = in_sizes[7] / H;      // 3
  const int Kc = H + in_sizes[2] / E;  // 192
  const int Kp = 96;

  const int* rows = eidx;
  const int* cols = eidx + E;

  char* ws = (char*)d_ws;
  size_t off = 0;
  auto alloc = [&](size_t bytes) { void* p = ws + off; off += (bytes + 255) / 256 * 256; return p; };
  __hip_bfloat16*  hbA      = (__hip_bfloat16*)alloc((size_t)N * 128 * 2);
  __hip_bfloat16*  hbB      = (__hip_bfloat16*)alloc((size_t)N * 128 * 2);
  unsigned char*   h8A      = (unsigned char*)alloc((size_t)N * 128);
  unsigned char*   h8B      = (unsigned char*)alloc((size_t)N * 128);
  __hip_bfloat16*  Tb       = (__hip_bfloat16*)alloc((size_t)N * 64 * 2);
  __hip_bfloat16*  Wet      = (__hip_bfloat16*)alloc((size_t)H * Kp * 2);
  __hip_bfloat16*  Wct      = (__hip_bfloat16*)alloc((size_t)L * H * Kc * 2);
  int*             row_ptr  = (int*)alloc((size_t)(N + 1) * 4);
  int*             cnt      = (int*)alloc((size_t)N * 4 * 2);
  int*             fill_cnt = cnt + N;
  int*             part     = (int*)alloc(64 * 4);
  int*             csr_col  = (int*)alloc((size_t)E * 4);
  int*             csr_eid  = (int*)alloc((size_t)E * 4);
  (void)ws_size; (void)n_in;

  hipMemsetAsync(cnt, 0, (size_t)N * 8, stream);

  // K1: weight convert || histogram
  const int wtot = H * Kp + L * H * Kc;
  const int wb   = (wtot + 255) / 256;
  const int hbk  = (E + 255) / 256;
  prep_hist<<<dim3(wb + hbk), 256, 0, stream>>>(
      W_emb, Wet, Wc, Wct, rows, cnt, E, wb, Fn, Kp, H, L, Kc);

  // two-phase parallel scan (SB <= 64 for N <= 131072)
  const int SB = (N + 2047) / 2048;
  scan_part<<<dim3(SB), 256, 0, stream>>>(cnt, row_ptr, part, N);
  scan_add<<<dim3(SB), 256, 0, stream>>>(row_ptr, part, N, SB);

  // K3: CSR fill || embedding GEMM (writes hbA + h8A)
  const int fb  = (E + 255) / 256;
  const int eb  = (N + 63) / 64;
  fill_emb<<<dim3(fb + eb), 256, 0, stream>>>(
      rows, cols, row_ptr, fill_cnt, csr_col, csr_eid, E, fb,
      x, Wet, b_emb, hbA, h8A, N, Fn);

  // conv layers (32-row tiles, static, fp8 gather + nt streams; l0 folds T)
  conv_fused<true><<<dim3((N + 31) / 32), 256, 0, stream>>>(
      hbA, h8A, row_ptr, csr_col, csr_eid, eattr, Tb, Wct,
      bc, gamma, beta, hbB, h8B, N);
  conv_fused<false><<<dim3((N + 31) / 32), 256, 0, stream>>>(
      hbB, h8B, row_ptr, csr_col, csr_eid, eattr, Tb, Wct + (size_t)H * Kc,
      bc + H, gamma + H, beta + H, hbA, h8A, N);
  conv_fused<false><<<dim3((N + 31) / 32), 256, 0, stream>>>(
      hbA, h8A, row_ptr, csr_col, csr_eid, eattr, Tb, Wct + (size_t)2 * H * Kc,
      bc + 2 * H, gamma + 2 * H, beta + 2 * H, hbB, h8B, N);

  pool_head<<<dim3(out_size), 256, 0, stream>>>(hbB, batch, Wh, bh, Wout, bout, out, N);
}

// Round 16
// 324.417 us; speedup vs baseline: 1.2042x; 1.2042x over previous
//
#include <hip/hip_runtime.h>
#include <hip/hip_bf16.h>
#include <cstdint>
#include <cstddef>

#define BN_EPS 1e-3f

typedef __attribute__((ext_vector_type(8))) short bf16x8;
typedef __attribute__((ext_vector_type(4))) float f32x4;
typedef __attribute__((ext_vector_type(2))) float f32x2;

__device__ __forceinline__ float blo(unsigned u) {
  union { unsigned i; float f; } v; v.i = u << 16; return v.f;
}
__device__ __forceinline__ float bhi(unsigned u) {
  union { unsigned i; float f; } v; v.i = u & 0xffff0000u; return v.f;
}
__device__ __forceinline__ unsigned pk2(float a, float b) {
  __hip_bfloat162 t = __float22bfloat162_rn(make_float2(a, b));
  return *reinterpret_cast<unsigned*>(&t);
}
// fp8 e4m3 (gfx950 OCP) helpers — self-consistent HW round-trip
__device__ __forceinline__ unsigned char to_fp8(float f) {
  unsigned v = __builtin_amdgcn_cvt_pk_fp8_f32(f, f, 0, false);
  return (unsigned char)(v & 0xffu);
}
__device__ __forceinline__ void acc_fp8(float* acc, uint2 u) {
  f32x2 p0 = __builtin_amdgcn_cvt_pk_f32_fp8(u.x, false);
  f32x2 p1 = __builtin_amdgcn_cvt_pk_f32_fp8(u.x, true);
  f32x2 p2 = __builtin_amdgcn_cvt_pk_f32_fp8(u.y, false);
  f32x2 p3 = __builtin_amdgcn_cvt_pk_f32_fp8(u.y, true);
  acc[0] += p0.x; acc[1] += p0.y; acc[2] += p1.x; acc[3] += p1.y;
  acc[4] += p2.x; acc[5] += p2.y; acc[6] += p3.x; acc[7] += p3.y;
}

// ---------------------------------------------------------------------------
// Embedding MFMA tile body (shared by fill_emb). Reads x fp32, cvt in-reg.
// hb = bf16(relu(x @ Wet^T + bias)); h8 = fp8(same). 64x128 tile, 4 waves.
// ---------------------------------------------------------------------------
__device__ __forceinline__ void emb_tile(
    const float* __restrict__ x,
    const __hip_bfloat16* __restrict__ Bt,   // [128][96]
    const float* __restrict__ bias,
    __hip_bfloat16* __restrict__ hb,
    unsigned char* __restrict__ h8, int N, int Fn, int m0, int tid)
{
  constexpr int KP = 96;
  const int w    = tid >> 6, lane = tid & 63;
  const int wr   = w >> 1,   wc   = w & 1;
  const int lr   = lane & 15;
  const int kg   = lane >> 4;

  f32x4 acc[2][4] = {};
  const int rowA0 = m0 + wr * 32 + lr;

  #pragma unroll
  for (int ks = 0; ks < KP / 32; ks++) {
    const int k0 = ks * 32 + kg * 8;
    bf16x8 a[2], b[4];
    #pragma unroll
    for (int m = 0; m < 2; m++) {
      int r = rowA0 + m * 16;
      r = (r < N) ? r : 0;
      const float* px = &x[(size_t)r * Fn + k0];
      float4 v0 = make_float4(0.f, 0.f, 0.f, 0.f);
      float4 v1 = make_float4(0.f, 0.f, 0.f, 0.f);
      if (k0 + 8 <= Fn) {
        v0 = *reinterpret_cast<const float4*>(px);
        v1 = *reinterpret_cast<const float4*>(px + 4);
      } else if (k0 + 4 <= Fn) {
        v0 = *reinterpret_cast<const float4*>(px);
        if (k0 + 5 <= Fn) v1.x = px[4];
        if (k0 + 6 <= Fn) v1.y = px[5];
        if (k0 + 7 <= Fn) v1.z = px[6];
      } else if (k0 < Fn) {
        if (k0 + 1 <= Fn) v0.x = px[0];
        if (k0 + 2 <= Fn) v0.y = px[1];
        if (k0 + 3 <= Fn) v0.z = px[2];
      }
      uint4 pu;
      pu.x = pk2(v0.x, v0.y); pu.y = pk2(v0.z, v0.w);
      pu.z = pk2(v1.x, v1.y); pu.w = pk2(v1.z, v1.w);
      a[m] = *reinterpret_cast<bf16x8*>(&pu);
    }
    #pragma unroll
    for (int n = 0; n < 4; n++) {
      int c = wc * 64 + n * 16 + lr;
      b[n] = *reinterpret_cast<const bf16x8*>(&Bt[(size_t)c * KP + k0]);
    }
    #pragma unroll
    for (int m = 0; m < 2; m++)
      #pragma unroll
      for (int n = 0; n < 4; n++)
        acc[m][n] = __builtin_amdgcn_mfma_f32_16x16x32_bf16(a[m], b[n], acc[m][n], 0, 0, 0);
  }

  #pragma unroll
  for (int n = 0; n < 4; n++) {
    const int c = wc * 64 + n * 16 + lr;
    const float bb = bias[c];
    #pragma unroll
    for (int m = 0; m < 2; m++) {
      #pragma unroll
      for (int j = 0; j < 4; j++) {
        int grow = m0 + wr * 32 + m * 16 + kg * 4 + j;
        if (grow < N) {
          float v = fmaxf(acc[m][n][j] + bb, 0.f);
          hb[(size_t)grow * 128 + c] = __float2bfloat16(v);
          h8[(size_t)grow * 128 + c] = to_fp8(v);
        }
      }
    }
  }
}

// ---------------------------------------------------------------------------
// Fused conv layer, bf16 residual chain, 32-row tiles, 16-deep gather MLP.
// Gather reads the fp8 shadow h8i (128B/row, halves random traffic); the
// residual read and output stay bf16; h8o written for the next layer.
//   hbo = bf16( hbi + relu( (gather(h8i) ++ T) @ Wct / deg * bn_scale + ofs ) )
// GATHER_T=true (layer 0): T gathered from eattr (free: overlaps hb burst).
// ---------------------------------------------------------------------------
template<bool GATHER_T>
__global__ __launch_bounds__(256) void conv_fused(
    const __hip_bfloat16* __restrict__ hbi,
    const unsigned char* __restrict__ h8i,
    const int* __restrict__ row_ptr,
    const int* __restrict__ csr_col,
    const int* __restrict__ csr_eid,
    const float* __restrict__ eattr,
    __hip_bfloat16* __restrict__ Tb,          // [N][64] out (l0) / in (l1,l2)
    const __hip_bfloat16* __restrict__ Wct,   // [128][192]
    const float* __restrict__ bc,
    const float* __restrict__ gamma,
    const float* __restrict__ beta,
    __hip_bfloat16* __restrict__ hbo,
    unsigned char* __restrict__ h8o, int N)
{
  constexpr int K   = 192;
  constexpr int LDK = 200;
  __shared__ __hip_bfloat16 As[32 * LDK];   // 12.8 KB
  __shared__ float sinv[32];

  const int tid = threadIdx.x;
  const int m0  = blockIdx.x * 32;

  // ---- gather phase: 16 groups x 16 lanes, static 2 rows per group
  {
    const int g   = tid >> 4;
    const int gl  = tid & 15;
    const int gb  = (tid & 63) & ~15;    // group base lane within wave (for shfl)

    #pragma unroll
    for (int rr = 0; rr < 2; rr++) {
      const int r  = g + rr * 16;
      const int gr = m0 + r;
      float acc[8] = {};
      float tacc[4] = {};
      int len = 0;
      if (gr < N) {
        const int s = row_ptr[gr];
        len = row_ptr[gr + 1] - s;
        for (int b = 0; b < len; b += 16) {
          const int m  = min(16, len - b);
          const int cv = (gl < m) ? csr_col[s + b + gl] : 0;
          int ev = 0;
          if (GATHER_T) ev = (gl < m) ? csr_eid[s + b + gl] : 0;
          int j = 0;
          for (; j + 16 <= m; j += 16) {
            uint2 u[16];
            #pragma unroll
            for (int t = 0; t < 16; t++) {
              int c = __shfl(cv, gb + j + t);
              u[t] = *reinterpret_cast<const uint2*>(&h8i[(size_t)c * 128 + gl * 8]);
            }
            #pragma unroll
            for (int t = 0; t < 16; t++) acc_fp8(acc, u[t]);
          }
          for (; j + 8 <= m; j += 8) {
            uint2 u[8];
            #pragma unroll
            for (int t = 0; t < 8; t++) {
              int c = __shfl(cv, gb + j + t);
              u[t] = *reinterpret_cast<const uint2*>(&h8i[(size_t)c * 128 + gl * 8]);
            }
            #pragma unroll
            for (int t = 0; t < 8; t++) acc_fp8(acc, u[t]);
          }
          for (; j + 4 <= m; j += 4) {
            uint2 u[4];
            #pragma unroll
            for (int t = 0; t < 4; t++) {
              int c = __shfl(cv, gb + j + t);
              u[t] = *reinterpret_cast<const uint2*>(&h8i[(size_t)c * 128 + gl * 8]);
            }
            #pragma unroll
            for (int t = 0; t < 4; t++) acc_fp8(acc, u[t]);
          }
          for (; j < m; ++j) {
            int c = __shfl(cv, gb + j);
            uint2 u = *reinterpret_cast<const uint2*>(&h8i[(size_t)c * 128 + gl * 8]);
            acc_fp8(acc, u);
          }
          if (GATHER_T) {
            int j2 = 0;
            for (; j2 + 16 <= m; j2 += 16) {
              float4 t4[16];
              #pragma unroll
              for (int t = 0; t < 16; t++) {
                int e0 = __shfl(ev, gb + j2 + t);
                t4[t] = *reinterpret_cast<const float4*>(&eattr[(size_t)e0 * 64 + gl * 4]);
              }
              #pragma unroll
              for (int t = 0; t < 16; t++) {
                tacc[0] += t4[t].x; tacc[1] += t4[t].y;
                tacc[2] += t4[t].z; tacc[3] += t4[t].w;
              }
            }
            for (; j2 + 4 <= m; j2 += 4) {
              float4 t4[4];
              #pragma unroll
              for (int t = 0; t < 4; t++) {
                int e0 = __shfl(ev, gb + j2 + t);
                t4[t] = *reinterpret_cast<const float4*>(&eattr[(size_t)e0 * 64 + gl * 4]);
              }
              #pragma unroll
              for (int t = 0; t < 4; t++) {
                tacc[0] += t4[t].x; tacc[1] += t4[t].y;
                tacc[2] += t4[t].z; tacc[3] += t4[t].w;
              }
            }
            for (; j2 < m; ++j2) {
              int e0 = __shfl(ev, gb + j2);
              float4 t0 = *reinterpret_cast<const float4*>(&eattr[(size_t)e0 * 64 + gl * 4]);
              tacc[0] += t0.x; tacc[1] += t0.y; tacc[2] += t0.z; tacc[3] += t0.w;
            }
          }
        }
      }
      uint4 o;
      o.x = pk2(acc[0], acc[1]); o.y = pk2(acc[2], acc[3]);
      o.z = pk2(acc[4], acc[5]); o.w = pk2(acc[6], acc[7]);
      *reinterpret_cast<uint4*>(&As[r * LDK + gl * 8]) = o;
      if (GATHER_T) {
        uint2 tw;
        tw.x = pk2(tacc[0], tacc[1]); tw.y = pk2(tacc[2], tacc[3]);
        *reinterpret_cast<uint2*>(&As[r * LDK + 128 + gl * 4]) = tw;
        if (gr < N)
          *reinterpret_cast<uint2*>(&Tb[(size_t)gr * 64 + gl * 4]) = tw;
      }
      if (gl == 0) sinv[r] = 1.f / fmaxf(1.f, (float)len);
    }
  }
  if (!GATHER_T) {
    // ---- T-tile copy: 32 rows x 64 cols bf16 = 256 x 16B chunks
    int r   = tid >> 3;
    int ko  = (tid & 7) * 8;
    int gr  = m0 + r;
    uint4 v = make_uint4(0, 0, 0, 0);
    if (gr < N) v = *reinterpret_cast<const uint4*>(&Tb[(size_t)gr * 64 + ko]);
    *reinterpret_cast<uint4*>(&As[r * LDK + 128 + ko]) = v;
  }
  __syncthreads();

  // ---- MFMA phase: 4 waves, wave w owns cols [w*32, w*32+32)
  const int w    = tid >> 6, lane = tid & 63;
  const int lr   = lane & 15;
  const int kg   = lane >> 4;

  f32x4 acc[2][2] = {};
  #pragma unroll
  for (int ks = 0; ks < K / 32; ks++) {
    const int k0 = ks * 32 + kg * 8;
    bf16x8 a[2], b[2];
    #pragma unroll
    for (int m = 0; m < 2; m++)
      a[m] = *reinterpret_cast<const bf16x8*>(&As[(lr + m * 16) * LDK + k0]);
    #pragma unroll
    for (int n = 0; n < 2; n++) {
      int c = w * 32 + n * 16 + lr;
      b[n] = *reinterpret_cast<const bf16x8*>(&Wct[(size_t)c * K + k0]);
    }
    #pragma unroll
    for (int m = 0; m < 2; m++)
      #pragma unroll
      for (int n = 0; n < 2; n++)
        acc[m][n] = __builtin_amdgcn_mfma_f32_16x16x32_bf16(a[m], b[n], acc[m][n], 0, 0, 0);
  }

  const float rs = rsqrtf(1.f + BN_EPS);
  #pragma unroll
  for (int n = 0; n < 2; n++) {
    const int c   = w * 32 + n * 16 + lr;
    const float sc  = gamma[c] * rs;
    const float ofs = bc[c] * sc + beta[c];
    #pragma unroll
    for (int m = 0; m < 2; m++) {
      #pragma unroll
      for (int j = 0; j < 4; j++) {
        int lrow = m * 16 + kg * 4 + j;
        int grow = m0 + lrow;
        if (grow < N) {
          float v    = acc[m][n][j] * sc * sinv[lrow] + ofs;
          float hold = __bfloat162float(hbi[(size_t)grow * 128 + c]);
          float hn   = hold + fmaxf(v, 0.f);
          hbo[(size_t)grow * 128 + c] = __float2bfloat16(hn);
          h8o[(size_t)grow * 128 + c] = to_fp8(hn);
        }
      }
    }
  }
}

// ---------------------------------------------------------------------------
// K1: blocks [0,wb) convert weights; blocks [wb,..) histogram row degrees
// (cnt pre-zeroed by memsetAsync).
// ---------------------------------------------------------------------------
__global__ void prep_hist(
    const float* __restrict__ W_emb, __hip_bfloat16* __restrict__ Wet,
    const float* __restrict__ Wc, __hip_bfloat16* __restrict__ Wct,
    const int* __restrict__ rows, int* __restrict__ cnt,
    int E, int wb, int Fn, int Kp, int H, int L, int Kc)
{
  if ((int)blockIdx.x < wb) {
    int i = blockIdx.x * 256 + threadIdx.x;
    if (i < H * Kp) {
      int c = i / Kp, k = i - c * Kp;
      Wet[i] = __float2bfloat16(k < Fn ? W_emb[(size_t)k * H + c] : 0.f);
    } else if (i < H * Kp + L * H * Kc) {
      int j = i - H * Kp;
      int l   = j / (H * Kc);
      int rem = j - l * (H * Kc);
      int c   = rem / Kc;
      int k   = rem - c * Kc;
      Wct[j] = __float2bfloat16(Wc[(size_t)l * Kc * H + (size_t)k * H + c]);
    }
  } else {
    int e = (blockIdx.x - wb) * 256 + threadIdx.x;
    if (e < E) atomicAdd(&cnt[rows[e]], 1);
  }
}

// ---------------------------------------------------------------------------
// Multi-block scan, phase 1: per-block (2048 elems) local inclusive scan into
// row_ptr[idx+1]; block total into part[b].
// ---------------------------------------------------------------------------
__global__ __launch_bounds__(256) void scan_part(
    const int* __restrict__ cnt, int* __restrict__ row_ptr,
    int* __restrict__ part, int M)
{
  __shared__ int wsum[4];
  const int tid  = threadIdx.x;
  const int lane = tid & 63, wid = tid >> 6;
  const int base = blockIdx.x * 2048;

  int v[8]; int s = 0;
  #pragma unroll
  for (int i = 0; i < 8; i++) {
    int idx = base + tid * 8 + i;
    v[i] = (idx < M) ? cnt[idx] : 0;
    s += v[i];
  }
  int sc = s;
  #pragma unroll
  for (int o = 1; o < 64; o <<= 1) {
    int u = __shfl_up(sc, o);
    if (lane >= o) sc += u;
  }
  if (lane == 63) wsum[wid] = sc;
  __syncthreads();
  int woff = 0;
  #pragma unroll
  for (int i = 0; i < 4; i++) if (i < wid) woff += wsum[i];
  int run = woff + (sc - s);
  #pragma unroll
  for (int i = 0; i < 8; i++) {
    int idx = base + tid * 8 + i;
    run += v[i];
    if (idx < M) row_ptr[idx + 1] = run;
  }
  if (tid == 0) part[blockIdx.x] = wsum[0] + wsum[1] + wsum[2] + wsum[3];
}

// ---------------------------------------------------------------------------
// Multi-block scan, phase 2: add exclusive-prefix of part[] to each segment.
// ---------------------------------------------------------------------------
__global__ __launch_bounds__(256) void scan_add(
    int* __restrict__ row_ptr, const int* __restrict__ part, int M, int SB)
{
  __shared__ int soff;
  const int b   = blockIdx.x;
  const int tid = threadIdx.x;
  if (tid < 64) {
    int x = (tid < b) ? part[tid] : 0;   // SB <= 64 assumed
    #pragma unroll
    for (int o = 32; o > 0; o >>= 1) x += __shfl_down(x, o);
    if (tid == 0) { soff = x; if (b == 0) row_ptr[0] = 0; }
  }
  __syncthreads();
  const int off  = soff;
  const int base = b * 2048;
  if (off != 0) {
    #pragma unroll
    for (int i = 0; i < 8; i++) {
      int idx = base + i * 256 + tid;
      if (idx < M) row_ptr[idx + 1] += off;
    }
  }
}

// ---------------------------------------------------------------------------
// K3: blocks [0,fb) CSR-fill; blocks [fb,..) embedding MFMA tiles.
// ---------------------------------------------------------------------------
__global__ __launch_bounds__(256) void fill_emb(
    const int* __restrict__ rows, const int* __restrict__ cols,
    const int* __restrict__ row_ptr, int* __restrict__ fill_cnt,
    int* __restrict__ csr_col, int* __restrict__ csr_eid, int E, int fb,
    const float* __restrict__ x, const __hip_bfloat16* __restrict__ Wet,
    const float* __restrict__ b_emb, __hip_bfloat16* __restrict__ hb,
    unsigned char* __restrict__ h8, int N, int Fn)
{
  if ((int)blockIdx.x < fb) {
    int e = blockIdx.x * 256 + threadIdx.x;
    if (e < E) {
      int r   = rows[e];
      int pos = atomicAdd(&fill_cnt[r], 1);
      int at  = row_ptr[r] + pos;
      csr_col[at] = cols[e];
      csr_eid[at] = e;
    }
  } else {
    emb_tile(x, Wet, b_emb, hb, h8, N, Fn, (blockIdx.x - fb) * 64, threadIdx.x);
  }
}

// ---------------------------------------------------------------------------
// Per-graph mean pool (bf16 h) + hidden relu + output head. One 256-thread
// block per graph: 4-way row striping for the pool, split-K hidden layer.
// ---------------------------------------------------------------------------
__global__ __launch_bounds__(256) void pool_head(
    const __hip_bfloat16* __restrict__ hb, const int* __restrict__ batch,
    const float* __restrict__ Wh, const float* __restrict__ bh,
    const float* __restrict__ Wout, const float* __restrict__ bout,
    float* __restrict__ out, int N)
{
  const int g = blockIdx.x;
  const int t = threadIdx.x;
  int lo = 0, hi = N;
  while (lo < hi) { int mid = (lo + hi) >> 1; if (batch[mid] < g) lo = mid + 1; else hi = mid; }
  int start = lo;
  hi = N;
  while (lo < hi) { int mid = (lo + hi) >> 1; if (batch[mid] < g + 1) lo = mid + 1; else hi = mid; }
  int end = lo;

  const int lane = t & 63, q = t >> 6;   // 4 quarters
  float2 a0 = {0.f, 0.f}, a1 = {0.f, 0.f};
  int i = start + q;
  for (; i + 4 < end; i += 8) {
    unsigned u0 = *reinterpret_cast<const unsigned*>(&hb[(size_t)(i + 0) * 128 + lane * 2]);
    unsigned u1 = *reinterpret_cast<const unsigned*>(&hb[(size_t)(i + 4) * 128 + lane * 2]);
    a0.x += blo(u0); a0.y += bhi(u0);
    a1.x += blo(u1); a1.y += bhi(u1);
  }
  for (; i < end; i += 4) {
    unsigned u = *reinterpret_cast<const unsigned*>(&hb[(size_t)i * 128 + lane * 2]);
    a0.x += blo(u); a0.y += bhi(u);
  }
  float2 sum;
  sum.x = a0.x + a1.x;
  sum.y = a0.y + a1.y;

  __shared__ float2 part[4][64];
  __shared__ float  gl[128];
  part[q][lane] = sum;
  __syncthreads();
  if (t < 64) {
    float inv = 1.f / fmaxf(1.f, (float)(end - start));
    float2 tot;
    tot.x = ((part[0][t].x + part[1][t].x) + (part[2][t].x + part[3][t].x));
    tot.y = ((part[0][t].y + part[1][t].y) + (part[2][t].y + part[3][t].y));
    gl[2 * t]     = tot.x * inv;
    gl[2 * t + 1] = tot.y * inv;
  }
  __syncthreads();

  // hidden layer split-K: thread t handles output f = t&127, k-half = t>>7
  const int f    = t & 127;
  const int half = t >> 7;
  float acc = 0.f;
  #pragma unroll 4
  for (int k = half * 64; k < half * 64 + 64; k++) acc += gl[k] * Wh[k * 128 + f];
  __shared__ float ph[2][128];
  ph[half][f] = acc;
  __syncthreads();

  __shared__ float p[128];
  if (t < 128) {
    float v = fmaxf(ph[0][t] + ph[1][t] + bh[t], 0.f);
    p[t] = v * Wout[t];
  }
  __syncthreads();
  if (t < 64) {
    float v = p[t] + p[t + 64];
    #pragma unroll
    for (int o = 32; o > 0; o >>= 1) v += __shfl_down(v, o);
    if (t == 0) out[g] = v + bout[0];
  }
}

// ---------------------------------------------------------------------------
extern "C" void kernel_launch(void* const* d_in, const int* in_sizes, int n_in,
                              void* d_out, int out_size, void* d_ws, size_t ws_size,
                              hipStream_t stream)
{
  const float* x      = (const float*)d_in[0];
  const int*   eidx   = (const int*)d_in[1];
  const float* eattr  = (const float*)d_in[2];
  const int*   batch  = (const int*)d_in[3];
  const float* W_emb  = (const float*)d_in[4];
  const float* b_emb  = (const float*)d_in[5];
  const float* Wc     = (const float*)d_in[6];
  const float* bc     = (const float*)d_in[7];
  const float* gamma  = (const float*)d_in[8];
  const float* beta   = (const float*)d_in[9];
  const float* Wh     = (const float*)d_in[10];
  const float* bh     = (const float*)d_in[11];
  const float* Wout   = (const float*)d_in[12];
  const float* bout   = (const float*)d_in[13];
  float* out = (float*)d_out;

  const int N  = in_sizes[3];
  const int E  = in_sizes[1] / 2;
  const int Fn = in_sizes[0] / N;      // 92
  const int H  = in_sizes[5];          // 128
  const int L  = in_sizes[7] / H;      // 3
  const int Kc = H + in_sizes[2] / E;  // 192
  const int Kp = 96;

  const int* rows = eidx;
  const int* cols = eidx + E;

  char* ws = (char*)d_ws;
  size_t off = 0;
  auto alloc = [&](size_t bytes) { void* p = ws + off; off += (bytes + 255) / 256 * 256; return p; };
  __hip_bfloat16*  hbA      = (__hip_bfloat16*)alloc((size_t)N * 128 * 2);
  __hip_bfloat16*  hbB      = (__hip_bfloat16*)alloc((size_t)N * 128 * 2);
  unsigned char*   h8A      = (unsigned char*)alloc((size_t)N * 128);
  unsigned char*   h8B      = (unsigned char*)alloc((size_t)N * 128);
  __hip_bfloat16*  Tb       = (__hip_bfloat16*)alloc((size_t)N * 64 * 2);
  __hip_bfloat16*  Wet      = (__hip_bfloat16*)alloc((size_t)H * Kp * 2);
  __hip_bfloat16*  Wct      = (__hip_bfloat16*)alloc((size_t)L * H * Kc * 2);
  int*             row_ptr  = (int*)alloc((size_t)(N + 1) * 4);
  int*             cnt      = (int*)alloc((size_t)N * 4 * 2);
  int*             fill_cnt = cnt + N;
  int*             part     = (int*)alloc(64 * 4);
  int*             csr_col  = (int*)alloc((size_t)E * 4);
  int*             csr_eid  = (int*)alloc((size_t)E * 4);
  (void)ws_size; (void)n_in;

  hipMemsetAsync(cnt, 0, (size_t)N * 8, stream);

  // K1: weight convert || histogram
  const int wtot = H * Kp + L * H * Kc;
  const int wb   = (wtot + 255) / 256;
  const int hbk  = (E + 255) / 256;
  prep_hist<<<dim3(wb + hbk), 256, 0, stream>>>(
      W_emb, Wet, Wc, Wct, rows, cnt, E, wb, Fn, Kp, H, L, Kc);

  // two-phase parallel scan (SB <= 64 for N <= 131072)
  const int SB = (N + 2047) / 2048;
  scan_part<<<dim3(SB), 256, 0, stream>>>(cnt, row_ptr, part, N);
  scan_add<<<dim3(SB), 256, 0, stream>>>(row_ptr, part, N, SB);

  // K3: CSR fill || embedding GEMM (writes hbA + h8A)
  const int fb  = (E + 255) / 256;
  const int eb  = (N + 63) / 64;
  fill_emb<<<dim3(fb + eb), 256, 0, stream>>>(
      rows, cols, row_ptr, fill_cnt, csr_col, csr_eid, E, fb,
      x, Wet, b_emb, hbA, h8A, N, Fn);

  // conv layers (32-row tiles, static, fp8 gather; layer 0 folds T gather)
  conv_fused<true><<<dim3((N + 31) / 32), 256, 0, stream>>>(
      hbA, h8A, row_ptr, csr_col, csr_eid, eattr, Tb, Wct,
      bc, gamma, beta, hbB, h8B, N);
  conv_fused<false><<<dim3((N + 31) / 32), 256, 0, stream>>>(
      hbB, h8B, row_ptr, csr_col, csr_eid, eattr, Tb, Wct + (size_t)H * Kc,
      bc + H, gamma + H, beta + H, hbA, h8A, N);
  conv_fused<false><<<dim3((N + 31) / 32), 256, 0, stream>>>(
      hbA, h8A, row_ptr, csr_col, csr_eid, eattr, Tb, Wct + (size_t)2 * H * Kc,
      bc + 2 * H, gamma + 2 * H, beta + 2 * H, hbB, h8B, N);

  pool_head<<<dim3(out_size), 256, 0, stream>>>(hbB, batch, Wh, bh, Wout, bout, out, N);
}